// Round 18
// baseline (584.688 us; speedup 1.0000x reference)
//
#include <hip/hip_runtime.h>
#include <cmath>

#define NS 64
#define NN 128
#define NT 1000
#define CH 8                                // steps per store burst
#define WROWS 130                           // 128 rows of w + 2 zero rows
#define WL_DW (WROWS * NN)                  // 16640
#define LDS_BYTES (WL_DW * 4 + 32)          // 66592 (w + mslot)

// == npy_logaddexpf(x, 0), branch-free but bit-identical:
//   x>0: fmax=x, |x|=x  -> x + log1p(exp(-x)) ; x<0: 0 + log1p(exp(x)) ; x==0 -> LOGE2
__device__ __forceinline__ float softplus_np(float x) {
    float r = fmaxf(x, 0.0f) + log1pf(expf(-fabsf(x)));
    return (x == 0.0f) ? 0.693147180559945309f : r;
}

// Barrier WITHOUT the compiler's vmcnt(0) drain: LDS-visibility only.
__device__ __forceinline__ void sync_lds() {
    __builtin_amdgcn_sched_barrier(0);
    asm volatile("s_waitcnt lgkmcnt(0)" ::: "memory");
    __builtin_amdgcn_s_barrier();
    __builtin_amdgcn_sched_barrier(0);
}

__global__ __launch_bounds__(128) void snn_scan_kernel(
    const float* __restrict__ w,
    const float* __restrict__ ic,
    const float* __restrict__ v0,
    const float* __restrict__ i0,
    const float* __restrict__ s0,
    const float* __restrict__ mu,
    const float* __restrict__ sigma,
    const float* __restrict__ noise,      // [T, S, N, 2]
    const float* __restrict__ exp_draws,  // [T, S, N]
    float* __restrict__ out)              // [S, N, T, 3]
{
    #pragma clang fp contract(off)
    extern __shared__ float smem[];
    float* wl = smem;                     // [130][128]: w rows + 2 zero rows
    unsigned long long* mslot =           // [2 parity][2 waves] spike masks
        (unsigned long long*)(smem + WL_DW);

    const int samp = blockIdx.x;
    const int tid  = threadIdx.x;
    const int wid  = tid >> 6;            // waves 0,1: both compute
    const int l    = tid & 63;
    const int n    = (wid << 6) | l;      // own neuron: 1 neuron/lane

    {   // stage w + zero rows (one-time, 128 threads)
        const float4* src = (const float4*)w;
        float4* dst = (float4*)wl;
        #pragma unroll
        for (int it = 0; it < 32; ++it)
            dst[it * 128 + tid] = src[it * 128 + tid];
        ((float2*)(wl + NN * NN))[tid] = make_float2(0.0f, 0.0f);
    }

    const float SQDT  = sqrtf(0.01f);     // 0x3DCCCCCD == np.sqrt(float32(0.01))
    const float DTf   = 0.01f;
    const float LOGE2 = 0.693147180559945309f;

    // lane-owned output run: out[samp][n][t][c]; per 8-step block this lane
    // writes 24 contiguous floats (96B, 16B-aligned) at outb + blk*24
    float* outb = out + ((size_t)samp * NN + n) * (NT * 3);

    float mu1, negmu2, g00, g01, g10, g11, icn;
    float v_, i_, s_, sp;
    float2 nb0, nb1, nb2, nb3, nb4, nb5, nb6, nb7;
    float  eb0, eb1, eb2, eb3, eb4, eb5, eb6, eb7;

    const float* nzb = noise + (size_t)samp * (NN * 2) + n * 2;   // + t*NS*NN*2
    const float* edb = exp_draws + (size_t)samp * NN + n;         // + t*NS*NN

    mu1 = mu[0]; negmu2 = -mu[1];
    g00 = sigma[0]; g01 = sigma[1]; g10 = sigma[2]; g11 = sigma[3];
    icn = ic[n];
    v_ = v0[samp * NN + n];
    i_ = i0[samp * NN + n];
    s_ = s0[samp * NN + n];
    sp = softplus_np(v_);
    nb0 = *(const float2*)(nzb + 0ull * (NS * NN * 2)); eb0 = edb[0ull * (NS * NN)];
    nb1 = *(const float2*)(nzb + 1ull * (NS * NN * 2)); eb1 = edb[1ull * (NS * NN)];
    nb2 = *(const float2*)(nzb + 2ull * (NS * NN * 2)); eb2 = edb[2ull * (NS * NN)];
    nb3 = *(const float2*)(nzb + 3ull * (NS * NN * 2)); eb3 = edb[3ull * (NS * NN)];
    nb4 = *(const float2*)(nzb + 4ull * (NS * NN * 2)); eb4 = edb[4ull * (NS * NN)];
    nb5 = *(const float2*)(nzb + 5ull * (NS * NN * 2)); eb5 = edb[5ull * (NS * NN)];
    nb6 = *(const float2*)(nzb + 6ull * (NS * NN * 2)); eb6 = edb[6ull * (NS * NN)];
    nb7 = *(const float2*)(nzb + 7ull * (NS * NN * 2)); eb7 = edb[7ull * (NS * NN)];

    sync_lds();                           // w + zero rows visible

    // 24 named staging registers (static indexing only — no scratch)
    float o0, o1, o2, o3, o4, o5, o6, o7, o8, o9, o10, o11,
          o12, o13, o14, o15, o16, o17, o18, o19, o20, o21, o22, o23;

    // STEP body; (OV,OI,OS) are the named staging regs for this k
    #define STEP(K, NB, EB, OV, OI, OS)                                        \
    {                                                                          \
        const int t = blk * CH + (K);                                          \
        /* pre-barrier: s-chain + spike-mask publish */                        \
        s_ = s_ + DTf * sp;                                                    \
        const bool kk = (s_ >= 0.0f);                                          \
        const unsigned long long mym = __ballot(kk);                           \
        if (l == 0) mslot[((K) & 1) * 2 + wid] = mym;                          \
        sync_lds();                                                            \
        /* post-barrier: drift + noise overlap the mask-read latency */        \
        const float2 nz = NB;                                                  \
        const float  ed = EB;                                                  \
        const int tp = (t + 8) < NT ? (t + 8) : NT - 1;                        \
        NB = *(const float2*)(nzb + (size_t)tp * (NS * NN * 2));               \
        EB = edb[(size_t)tp * (NS * NN)];                                      \
        const float dw0 = nz.x * SQDT, dw1 = nz.y * SQDT;                      \
        const float nv = (dw0 * g00) + (dw1 * g01);                            \
        const float ni = (dw0 * g10) + (dw1 * g11);                            \
        const float tt = (i_ + icn) - v_;                                      \
        const float vt = (v_ + DTf * (mu1 * tt)) + nv;                         \
        const float it = (i_ + DTf * (negmu2 * i_)) + ni;                      \
        const float spv = softplus_np(vt);                                     \
        unsigned long long m0 = mslot[((K) & 1) * 2 + 0];                      \
        unsigned long long m1 = mslot[((K) & 1) * 2 + 1];                      \
        float a = 0.0f;                                                        \
        if (m0 | m1) {                                                         \
            auto ext1 = [&]() -> int {                                         \
                const bool u0 = (m0 != 0);                                     \
                const unsigned long long m = u0 ? m0 : m1;                     \
                const int b = m ? (int)__builtin_ctzll(m) : 99;                \
                const int r = (b == 99) ? 128 : ((u0 ? 0 : 64) + b);           \
                const unsigned long long m0n = m0 & (m0 - 1);                  \
                const unsigned long long m1n = m1 & (m1 - 1);                  \
                m0 = u0 ? m0n : m0;                                            \
                m1 = u0 ? m1 : m1n;                                            \
                return r;                                                      \
            };                                                                 \
            const int r1 = ext1(); const int r2 = ext1();                      \
            const int r3 = ext1(); const int r4 = ext1();                      \
            const float q1 = wl[r1 * NN + n];                                  \
            const float q2 = wl[r2 * NN + n];                                  \
            const float q3 = wl[r3 * NN + n];                                  \
            const float q4 = wl[r4 * NN + n];                                  \
            a = q1;  a += q2;  a += q3;  a += q4;                              \
            _Pragma("clang loop unroll(disable)")                              \
            while (m0 | m1) {                                                  \
                const int r = ext1();                                          \
                a += wl[r * NN + n];                                           \
            }                                                                  \
        }                                                                      \
        i_ = it + a;                                                           \
        v_ = kk ? 0.0f : vt;                                                   \
        s_ = kk ? -ed : s_;                                                    \
        sp = kk ? LOGE2 : spv;                                                 \
        OV = v_; OI = i_; OS = s_;                                             \
    }

    #pragma clang loop unroll(disable)
    for (int blk = 0; blk < NT / CH; ++blk) {
        STEP(0, nb0, eb0, o0,  o1,  o2 );
        STEP(1, nb1, eb1, o3,  o4,  o5 );
        STEP(2, nb2, eb2, o6,  o7,  o8 );
        STEP(3, nb3, eb3, o9,  o10, o11);
        STEP(4, nb4, eb4, o12, o13, o14);
        STEP(5, nb5, eb5, o15, o16, o17);
        STEP(6, nb6, eb6, o18, o19, o20);
        STEP(7, nb7, eb7, o21, o22, o23);
        // direct store burst: 6x global_store_dwordx4, 96B contiguous per lane
        float* ob = outb + blk * (CH * 3);
        *(float4*)(ob +  0) = make_float4(o0,  o1,  o2,  o3 );
        *(float4*)(ob +  4) = make_float4(o4,  o5,  o6,  o7 );
        *(float4*)(ob +  8) = make_float4(o8,  o9,  o10, o11);
        *(float4*)(ob + 12) = make_float4(o12, o13, o14, o15);
        *(float4*)(ob + 16) = make_float4(o16, o17, o18, o19);
        *(float4*)(ob + 20) = make_float4(o20, o21, o22, o23);
    }
    #undef STEP
}

extern "C" void kernel_launch(void* const* d_in, const int* in_sizes, int n_in,
                              void* d_out, int out_size, void* d_ws, size_t ws_size,
                              hipStream_t stream) {
    const float* w         = (const float*)d_in[0];
    const float* ic        = (const float*)d_in[1];
    const float* v0        = (const float*)d_in[2];
    const float* i0        = (const float*)d_in[3];
    const float* s0        = (const float*)d_in[4];
    const float* mu        = (const float*)d_in[5];
    const float* sigma     = (const float*)d_in[6];
    const float* noise     = (const float*)d_in[7];
    const float* exp_draws = (const float*)d_in[8];
    float* out = (float*)d_out;

    (void)hipFuncSetAttribute((const void*)snn_scan_kernel,
                              hipFuncAttributeMaxDynamicSharedMemorySize,
                              LDS_BYTES);

    // 2 compute waves, 1 neuron/lane, register-staged direct output stores
    // (no flush wave, no obuf)
    snn_scan_kernel<<<dim3(NS), dim3(128), LDS_BYTES, stream>>>(
        w, ic, v0, i0, s0, mu, sigma, noise, exp_draws, out);
}